// Round 14
// baseline (154.716 us; speedup 1.0000x reference)
//
#include <hip/hip_runtime.h>

// GraphSAGE 2-layer + link predictor, layer-2 collapsed to 4 scalars/node.
// pre(count || xcast || prep) -> relscan_base (decoupled) -> scatter -> csr (LDS 1-pass)
// -> gather -> fused_gemm -> sgather -> linkpred.

typedef __attribute__((ext_vector_type(8))) short bf16x8;
typedef __attribute__((ext_vector_type(4))) float f32x4;

#define NBLK_A 256   // blocks in edge-chunk passes
#define CSR_LDS_CAP 5120

__device__ __forceinline__ unsigned short f2bf(float f) {
    unsigned u = __float_as_uint(f);
    u = u + 0x7fffu + ((u >> 16) & 1u);   // RTNE
    return (unsigned short)(u >> 16);
}
__device__ __forceinline__ float b2f(unsigned short s) {
    return __uint_as_float(((unsigned)s) << 16);
}
__device__ __forceinline__ float uflo(unsigned v) { return __uint_as_float(v << 16); }
__device__ __forceinline__ float ufhi(unsigned v) { return __uint_as_float(v & 0xffff0000u); }

__device__ __forceinline__ long load_idx(const void* p, long i, int is64) {
    if (is64) return (long)((const long long*)p)[i];
    return (long)((const int*)p)[i];
}

__device__ __forceinline__ int detect64_local(const void* p) {
    const unsigned* u = (const unsigned*)p;
    unsigned a = 0;
#pragma unroll
    for (int i = 0; i < 32; ++i) a |= u[2 * i + 1];
    return a == 0u;
}

// ---------------- pre: bucket_count || xcast || prep ----------------
__global__ void pre_kernel(const void* eidx, const float* __restrict__ x,
                           const float* __restrict__ W1l, const float* __restrict__ W1r,
                           const float* __restrict__ W2l, const float* __restrict__ W2r,
                           const float* __restrict__ b2, const float* __restrict__ Wlp,
                           const float* __restrict__ blp,
                           int* __restrict__ blk_hist, unsigned short* __restrict__ xaown,
                           unsigned short* __restrict__ w1bf, float* __restrict__ wv,
                           int* __restrict__ flag, int* __restrict__ done,
                           long N, long E, int NBK, int chunk, int xcb) {
    int b = blockIdx.x;
    int tid = threadIdx.x;
    if (b < NBLK_A) {
        __shared__ int h[512];
        for (int i = tid; i < NBK; i += 256) h[i] = 0;
        __syncthreads();
        int is64 = detect64_local(eidx);
        long e0 = (long)b * chunk;
        long e1 = e0 + chunk; if (e1 > E) e1 = E;
        long e = e0 + tid * 2;
        for (; e + 1 < e1; e += 512) {
            long d0 = load_idx(eidx, E + e, is64);
            long d1 = load_idx(eidx, E + e + 1, is64);
            atomicAdd(&h[(int)(d0 >> 8)], 1);
            atomicAdd(&h[(int)(d1 >> 8)], 1);
        }
        if (e < e1) {
            long d0 = load_idx(eidx, E + e, is64);
            atomicAdd(&h[(int)(d0 >> 8)], 1);
        }
        __syncthreads();
        for (int i = tid; i < NBK; i += 256) blk_hist[i * NBLK_A + b] = h[i];
    } else if (b < NBLK_A + xcb) {
        long t = (long)(b - NBLK_A) * 256 + tid;
        long n = t >> 4;
        int q = (int)(t & 15);
        if (n >= N) return;
        float4 v = *(const float4*)&x[n * 64 + q * 4];
        uint2 u;
        u.x = (unsigned)f2bf(v.x) | ((unsigned)f2bf(v.y) << 16);
        u.y = (unsigned)f2bf(v.z) | ((unsigned)f2bf(v.w) << 16);
        *(uint2*)&xaown[n * 64 + q * 4] = u;
    } else {
        if (tid == 0) { *flag = detect64_local(eidx); *done = 0; }
        if (tid < 128) {
            int k = tid;
            float s0 = 0.f, s1 = 0.f, s2 = 0.f, s3 = 0.f;
            for (int o = 0; o < 64; ++o) {
                float wl = Wlp[o], wr = Wlp[64 + o];
                float l = W2l[o * 128 + k], r = W2r[o * 128 + k];
                s0 += wl * l; s1 += wr * l; s2 += wl * r; s3 += wr * r;
            }
            wv[k] = s0; wv[128 + k] = s1; wv[256 + k] = s2; wv[384 + k] = s3;
            if (k == 0) {
                float c = blp[0];
                for (int o = 0; o < 64; ++o) c += (Wlp[o] + Wlp[64 + o]) * b2[o];
                wv[512] = c;
            }
        }
        // W1' bf16, PRE-SWIZZLED: element (o*128+k) stored at index ^ ((o&7)<<3)
        for (int i = tid; i < 16384; i += 256) {
            int o = i >> 7, k = i & 127;
            float f = (k < 64) ? W1l[o * 64 + k] : W1r[o * 64 + (k - 64)];
            w1bf[i ^ ((o & 7) << 3)] = f2bf(f);
        }
    }
}

// relscan + base, decoupled: each block scans its bucket row; last finished block
// (device-scope counter) performs the 512-wide exclusive scan of totals.
__global__ void relscan_base_kernel(int* __restrict__ blk_hist, int* __restrict__ total,
                                    int* __restrict__ base, int* __restrict__ row_start,
                                    int* __restrict__ done, int NBK, long N, long E) {
    __shared__ int ts[256];
    __shared__ int isLast;
    int k = blockIdx.x, t = threadIdx.x;
    int v = blk_hist[k * NBLK_A + t];
    ts[t] = v; __syncthreads();
    for (int off = 1; off < 256; off <<= 1) {
        int u = (t >= off) ? ts[t - off] : 0;
        __syncthreads();
        ts[t] += u;
        __syncthreads();
    }
    blk_hist[k * NBLK_A + t] = ts[t] - v;
    if (t == 255) total[k] = ts[255];
    __threadfence();
    __syncthreads();
    if (t == 0) isLast = (atomicAdd(done, 1) == gridDim.x - 1);
    __syncthreads();
    if (!isLast) return;
    __threadfence();
    // base scan over up to 512 totals
    int a = (t < NBK) ? total[t] : 0;
    int b = (256 + t < NBK) ? total[256 + t] : 0;
    ts[t] = a; __syncthreads();
    for (int off = 1; off < 256; off <<= 1) {
        int u = (t >= off) ? ts[t - off] : 0;
        __syncthreads();
        ts[t] += u;
        __syncthreads();
    }
    int incl1 = ts[t];
    int sum1 = ts[255];
    if (t < NBK) base[t] = incl1 - a;
    __syncthreads();
    ts[t] = b; __syncthreads();
    for (int off = 1; off < 256; off <<= 1) {
        int u = (t >= off) ? ts[t - off] : 0;
        __syncthreads();
        ts[t] += u;
        __syncthreads();
    }
    int incl2 = ts[t];
    if (256 + t < NBK) base[256 + t] = sum1 + incl2 - b;
    if (t == 255) base[NBK] = sum1 + incl2;
    if (t == 0) row_start[N] = (int)E;
}

// scatter: cursor = relative offset + base[k]; 2 edges/thread/iter.
__global__ void bucket_scatter_kernel(const void* eidx, const int* flag,
                                      const int* __restrict__ blk_hist, const int* __restrict__ base,
                                      unsigned* __restrict__ ebuf, long E, int NBK, int chunk) {
    __shared__ int cur[512];
    int tid = threadIdx.x, b = blockIdx.x;
    for (int i = tid; i < NBK; i += 256) cur[i] = blk_hist[i * NBLK_A + b] + base[i];
    __syncthreads();
    int is64 = *flag;
    long e0 = (long)b * chunk;
    long e1 = e0 + chunk; if (e1 > E) e1 = E;
    long e = e0 + tid * 2;
    for (; e + 1 < e1; e += 512) {
        long s0 = load_idx(eidx, e, is64);
        long s1 = load_idx(eidx, e + 1, is64);
        long d0 = load_idx(eidx, E + e, is64);
        long d1 = load_idx(eidx, E + e + 1, is64);
        int p0 = atomicAdd(&cur[(int)(d0 >> 8)], 1);
        ebuf[p0] = (unsigned)s0 | ((unsigned)(d0 & 255) << 24);
        int p1 = atomicAdd(&cur[(int)(d1 >> 8)], 1);
        ebuf[p1] = (unsigned)s1 | ((unsigned)(d1 & 255) << 24);
    }
    if (e < e1) {
        long s0 = load_idx(eidx, e, is64);
        long d0 = load_idx(eidx, E + e, is64);
        int p0 = atomicAdd(&cur[(int)(d0 >> 8)], 1);
        ebuf[p0] = (unsigned)s0 | ((unsigned)(d0 & 255) << 24);
    }
}

// per-bucket counting sort, single global read: edges staged in LDS (fallback if >CAP).
__global__ void bucket_csr_kernel(const unsigned* __restrict__ ebuf, const int* __restrict__ base,
                                  int* __restrict__ csr_src, int* __restrict__ row_start, long N) {
    __shared__ unsigned eL[CSR_LDS_CAP];
    __shared__ int cnt[256], sc[256], cur[256];
    int k = blockIdx.x, t = threadIdx.x;
    int bstart = base[k], bend = base[k + 1];
    int m = bend - bstart;
    cnt[t] = 0;
    __syncthreads();
    if (m <= CSR_LDS_CAP) {
        for (int i = t; i < m; i += 256) {
            unsigned v = ebuf[bstart + i];
            eL[i] = v;
            atomicAdd(&cnt[v >> 24], 1);
        }
    } else {
        for (int i = bstart + t; i < bend; i += 256)
            atomicAdd(&cnt[ebuf[i] >> 24], 1);
    }
    __syncthreads();
    int c = cnt[t];
    sc[t] = c; __syncthreads();
    for (int off = 1; off < 256; off <<= 1) {
        int u = (t >= off) ? sc[t - off] : 0;
        __syncthreads();
        sc[t] += u;
        __syncthreads();
    }
    int loff = sc[t] - c;
    cur[t] = loff;
    long n = (long)k * 256 + t;
    if (n < N) row_start[n] = bstart + loff;
    __syncthreads();
    if (m <= CSR_LDS_CAP) {
        for (int i = t; i < m; i += 256) {
            unsigned v = eL[i];
            int p = atomicAdd(&cur[v >> 24], 1);
            csr_src[bstart + p] = (int)(v & 0xFFFFFFu);
        }
    } else {
        for (int i = bstart + t; i < bend; i += 256) {
            unsigned v = ebuf[i];
            int p = atomicAdd(&cur[v >> 24], 1);
            csr_src[bstart + p] = (int)(v & 0xFFFFFFu);
        }
    }
}

// ---------------- gather: xagg[n][64] = mean_nbr xaown[src][64] ----------------
// One wave per node. 16 edges/iter, 16 lines in flight, 32-bit addressing.
__global__ void gather_kernel(const int* __restrict__ rs, const int* __restrict__ csr,
                              const unsigned short* __restrict__ T,
                              unsigned short* __restrict__ Out, long N) {
    long gid = (long)blockIdx.x * 256 + threadIdx.x;
    long n = gid >> 6;
    if (n >= N) return;
    int lane = (int)(gid & 63);
    int lg = lane >> 4;
    int fq = lane & 15;
    int s = rs[n], e = rs[n + 1];
    unsigned boff = (unsigned)fq * 4u;
    float a0 = 0.f, a1 = 0.f, a2 = 0.f, a3 = 0.f;
    int j = s;
    for (; j + 16 <= e; j += 16) {
        unsigned o0 = ((unsigned)csr[j + lg] << 6) | boff;
        unsigned o1 = ((unsigned)csr[j + 4 + lg] << 6) | boff;
        unsigned o2 = ((unsigned)csr[j + 8 + lg] << 6) | boff;
        unsigned o3 = ((unsigned)csr[j + 12 + lg] << 6) | boff;
        uint2 r0 = *(const uint2*)&T[o0];
        uint2 r1 = *(const uint2*)&T[o1];
        uint2 r2 = *(const uint2*)&T[o2];
        uint2 r3 = *(const uint2*)&T[o3];
        a0 += uflo(r0.x); a1 += ufhi(r0.x); a2 += uflo(r0.y); a3 += ufhi(r0.y);
        a0 += uflo(r1.x); a1 += ufhi(r1.x); a2 += uflo(r1.y); a3 += ufhi(r1.y);
        a0 += uflo(r2.x); a1 += ufhi(r2.x); a2 += uflo(r2.y); a3 += ufhi(r2.y);
        a0 += uflo(r3.x); a1 += ufhi(r3.x); a2 += uflo(r3.y); a3 += ufhi(r3.y);
    }
    if (j < e) {
#pragma unroll
        for (int t = 0; t < 4; ++t) {
            int pos = j + 4 * t + lg;
            int ok = pos < e;
            unsigned oo = ((unsigned)csr[ok ? pos : s] << 6) | boff;
            uint2 r = *(const uint2*)&T[oo];
            float m = ok ? 1.f : 0.f;
            a0 += m * uflo(r.x); a1 += m * ufhi(r.x);
            a2 += m * uflo(r.y); a3 += m * ufhi(r.y);
        }
    }
    a0 += __shfl_xor(a0, 16, 64);  a1 += __shfl_xor(a1, 16, 64);
    a2 += __shfl_xor(a2, 16, 64);  a3 += __shfl_xor(a3, 16, 64);
    a0 += __shfl_xor(a0, 32, 64);  a1 += __shfl_xor(a1, 32, 64);
    a2 += __shfl_xor(a2, 32, 64);  a3 += __shfl_xor(a3, 32, 64);
    if (lg == 0) {
        float inv = 1.0f / fmaxf((float)(e - s), 1.0f);
        uint2 o;
        o.x = (unsigned)f2bf(a0 * inv) | ((unsigned)f2bf(a1 * inv) << 16);
        o.y = (unsigned)f2bf(a2 * inv) | ((unsigned)f2bf(a3 * inv) << 16);
        *(uint2*)&Out[((unsigned)n << 6) | boff] = o;
    }
}

// ---------------- fused MFMA GEMM + collapse ----------------
__global__ __launch_bounds__(512) void fused_gemm_kernel(
        const unsigned short* __restrict__ xagg, const unsigned short* __restrict__ xaown,
        const unsigned short* __restrict__ w1bf, const float* __restrict__ b1,
        const float* __restrict__ wv,
        float* __restrict__ ab, float* __restrict__ cd, long N) {
    __shared__ __align__(16) unsigned short wbuf[128 * 128];
    __shared__ float bs1[128];
    __shared__ float wvs[512];
    int tid = threadIdx.x;

    {
        const uint4* src = (const uint4*)w1bf;
        uint4* dst = (uint4*)wbuf;
#pragma unroll
        for (int i = 0; i < 4; ++i) dst[tid + i * 512] = src[tid + i * 512];
    }
    if (tid < 128) bs1[tid] = b1[tid];
    wvs[tid] = wv[tid];
    __syncthreads();

    int lane = tid & 63, wid = tid >> 6;
    int l16 = lane & 15, lg = lane >> 4;
    long n0 = (long)blockIdx.x * 128 + wid * 16;
    const unsigned short* Ag = xagg + (n0 + l16) * 64;
    const unsigned short* Ao = xaown + (n0 + l16) * 64;

    f32x4 acc[8];
#pragma unroll
    for (int ot = 0; ot < 8; ++ot) acc[ot] = (f32x4){0.f, 0.f, 0.f, 0.f};

#pragma unroll
    for (int ks = 0; ks < 4; ++ks) {
        int k0 = ks * 32;
        bf16x8 a;
        if (ks < 2) a = *(const bf16x8*)&Ag[k0 + 8 * lg];
        else        a = *(const bf16x8*)&Ao[(k0 - 64) + 8 * lg];
#pragma unroll
        for (int ot = 0; ot < 8; ++ot) {
            int o = ot * 16 + l16;
            bf16x8 b = *(const bf16x8*)&wbuf[(o * 128 + k0 + 8 * lg) ^ ((o & 7) << 3)];
            acc[ot] = __builtin_amdgcn_mfma_f32_16x16x32_bf16(a, b, acc[ot], 0, 0, 0);
        }
    }

#pragma unroll
    for (int j = 0; j < 4; ++j) {
        float da = 0.f, db = 0.f, dc = 0.f, dd = 0.f;
#pragma unroll
        for (int ot = 0; ot < 8; ++ot) {
            int col = ot * 16 + l16;
            float hv = fmaxf(acc[ot][j] + bs1[col], 0.f);
            da += hv * wvs[col];       db += hv * wvs[128 + col];
            dc += hv * wvs[256 + col]; dd += hv * wvs[384 + col];
        }
        da += __shfl_xor(da, 1, 64); db += __shfl_xor(db, 1, 64);
        dc += __shfl_xor(dc, 1, 64); dd += __shfl_xor(dd, 1, 64);
        da += __shfl_xor(da, 2, 64); db += __shfl_xor(db, 2, 64);
        dc += __shfl_xor(dc, 2, 64); dd += __shfl_xor(dd, 2, 64);
        da += __shfl_xor(da, 4, 64); db += __shfl_xor(db, 4, 64);
        dc += __shfl_xor(dc, 4, 64); dd += __shfl_xor(dd, 4, 64);
        da += __shfl_xor(da, 8, 64); db += __shfl_xor(db, 8, 64);
        dc += __shfl_xor(dc, 8, 64); dd += __shfl_xor(dd, 8, 64);
        long n = n0 + lg * 4 + j;
        if (l16 == 0 && n < N) {
            *(float2*)&ab[n * 2] = make_float2(da, db);
            *(float2*)&cd[n * 2] = make_float2(dc, dd);
        }
    }
}

// ---------------- scalar gather ----------------
__global__ void sgather_kernel(const int* __restrict__ rs, const int* __restrict__ csr,
                               const float* __restrict__ ab, const float* __restrict__ cd,
                               float* __restrict__ UV, long N) {
    long n = (long)blockIdx.x * 256 + threadIdx.x;
    if (n >= N) return;
    int s = rs[n], e = rs[n + 1];
    float sa = 0.f, sb = 0.f;
    int j = s;
    for (; j + 4 <= e; j += 4) {
        unsigned i0 = (unsigned)csr[j] * 2u, i1 = (unsigned)csr[j + 1] * 2u;
        unsigned i2 = (unsigned)csr[j + 2] * 2u, i3 = (unsigned)csr[j + 3] * 2u;
        float2 v0 = *(const float2*)&ab[i0];
        float2 v1 = *(const float2*)&ab[i1];
        float2 v2 = *(const float2*)&ab[i2];
        float2 v3 = *(const float2*)&ab[i3];
        sa += (v0.x + v1.x) + (v2.x + v3.x);
        sb += (v0.y + v1.y) + (v2.y + v3.y);
    }
    for (; j < e; ++j) {
        float2 v = *(const float2*)&ab[(unsigned)csr[j] * 2u];
        sa += v.x; sb += v.y;
    }
    float inv = 1.0f / fmaxf((float)(e - s), 1.0f);
    float2 cdv = *(const float2*)&cd[n * 2];
    *(float2*)&UV[n * 2] = make_float2(sa * inv + cdv.x, sb * inv + cdv.y);
}

// linkpred: out[p] = sigmoid(U[s] + V[d] + C)
__global__ void linkpred_kernel(const void* pairs, const int* flag,
                                const float* __restrict__ UV, const float* __restrict__ wv,
                                float* __restrict__ out, long P) {
    long p = (long)blockIdx.x * 256 + threadIdx.x;
    if (p >= P) return;
    int is64 = *flag;
    long s = load_idx(pairs, 2 * p, is64);
    long d = load_idx(pairs, 2 * p + 1, is64);
    float acc = UV[s * 2] + UV[d * 2 + 1] + wv[512];
    out[p] = 1.0f / (1.0f + expf(-acc));
}

extern "C" void kernel_launch(void* const* d_in, const int* in_sizes, int n_in,
                              void* d_out, int out_size, void* d_ws, size_t ws_size,
                              hipStream_t stream) {
    const float* x    = (const float*)d_in[0];
    const void*  eidx  = d_in[1];
    const void*  pairs = d_in[2];
    const float* W1l = (const float*)d_in[3];
    const float* W1r = (const float*)d_in[4];
    const float* b1  = (const float*)d_in[5];
    const float* W2l = (const float*)d_in[6];
    const float* W2r = (const float*)d_in[7];
    const float* b2  = (const float*)d_in[8];
    const float* Wlp = (const float*)d_in[9];
    const float* blp = (const float*)d_in[10];
    float* out = (float*)d_out;

    long N = in_sizes[0] / 64;
    long E = in_sizes[1] / 2;
    long P = in_sizes[2] / 2;
    long NP = (N + 127) & ~127L;
    int NBK = (int)((N + 255) >> 8);          // <= 512
    int chunk = (int)(((E + NBLK_A - 1) / NBLK_A + 1) & ~1L);   // even
    int xcb = (int)((N * 16 + 255) / 256);

    char* w = (char*)d_ws;
    auto alloc = [&](size_t bytes) {
        char* p = w;
        w += (bytes + 255) & ~(size_t)255;
        return p;
    };
    int* row_start = (int*)alloc((N + 1) * sizeof(int));
    int* csr_src   = (int*)alloc(E * sizeof(int));
    int* blk_hist  = (int*)alloc((size_t)NBK * NBLK_A * sizeof(int));
    int* total     = (int*)alloc(NBK * sizeof(int));
    int* base      = (int*)alloc((NBK + 1) * sizeof(int));
    int* flag      = (int*)alloc(64);
    int* done      = (int*)alloc(64);
    unsigned* ebuf = (unsigned*)alloc(E * sizeof(unsigned));
    unsigned short* xaown = (unsigned short*)alloc((size_t)NP * 64 * 2);
    unsigned short* xagg  = (unsigned short*)alloc((size_t)NP * 64 * 2);
    unsigned short* w1bf  = (unsigned short*)alloc(16384 * 2);
    float* ab = (float*)alloc((size_t)N * 2 * sizeof(float));
    float* cd = (float*)alloc((size_t)N * 2 * sizeof(float));
    float* UV = (float*)alloc((size_t)N * 2 * sizeof(float));
    float* wv = (float*)alloc(1024 * sizeof(float));

    unsigned pre_blocks = (unsigned)(NBLK_A + xcb + 1);
    pre_kernel<<<pre_blocks, 256, 0, stream>>>(eidx, x, W1l, W1r, W2l, W2r, b2, Wlp, blp,
                                               blk_hist, xaown, w1bf, wv, flag, done,
                                               N, E, NBK, chunk, xcb);

    relscan_base_kernel<<<NBK, 256, 0, stream>>>(blk_hist, total, base, row_start, done, NBK, N, E);
    bucket_scatter_kernel<<<NBLK_A, 256, 0, stream>>>(eidx, flag, blk_hist, base, ebuf, E, NBK, chunk);
    bucket_csr_kernel<<<NBK, 256, 0, stream>>>(ebuf, base, csr_src, row_start, N);

    unsigned gth_blocks = (unsigned)((N * 64 + 255) / 256);
    gather_kernel<<<gth_blocks, 256, 0, stream>>>(row_start, csr_src, xaown, xagg, N);

    unsigned gblocks = (unsigned)(NP / 128);
    fused_gemm_kernel<<<gblocks, 512, 0, stream>>>(xagg, xaown, w1bf, b1, wv, ab, cd, N);

    unsigned sgblocks = (unsigned)((N + 255) / 256);
    sgather_kernel<<<sgblocks, 256, 0, stream>>>(row_start, csr_src, ab, cd, UV, N);

    unsigned pblocks = (unsigned)((P + 255) / 256);
    linkpred_kernel<<<pblocks, 256, 0, stream>>>(pairs, flag, UV, wv, out, P);
}

// Round 15
// 132.057 us; speedup vs baseline: 1.1716x; 1.1716x over previous
//
#include <hip/hip_runtime.h>

// GraphSAGE 2-layer + link predictor, layer-2 collapsed to 4 scalars/node.
// pre(count || xcast || {flag,wv,W1'bf16}) -> relscan(+total) -> base -> scatter -> csr
// -> gather (xagg, 1 wave/node) -> fused_gemm (A from global, in-register collapse)
// -> sgather -> linkpred.
// EXACT round-13 configuration (measured 131.4 us) — round-14's 3-way change regressed.

typedef __attribute__((ext_vector_type(8))) short bf16x8;
typedef __attribute__((ext_vector_type(4))) float f32x4;

#define NBLK_A 256   // blocks in edge-chunk passes

__device__ __forceinline__ unsigned short f2bf(float f) {
    unsigned u = __float_as_uint(f);
    u = u + 0x7fffu + ((u >> 16) & 1u);   // RTNE
    return (unsigned short)(u >> 16);
}
__device__ __forceinline__ float b2f(unsigned short s) {
    return __uint_as_float(((unsigned)s) << 16);
}
__device__ __forceinline__ float uflo(unsigned v) { return __uint_as_float(v << 16); }
__device__ __forceinline__ float ufhi(unsigned v) { return __uint_as_float(v & 0xffff0000u); }

__device__ __forceinline__ long load_idx(const void* p, long i, int is64) {
    if (is64) return (long)((const long long*)p)[i];
    return (long)((const int*)p)[i];
}

__device__ __forceinline__ int detect64_local(const void* p) {
    const unsigned* u = (const unsigned*)p;
    unsigned a = 0;
#pragma unroll
    for (int i = 0; i < 32; ++i) a |= u[2 * i + 1];
    return a == 0u;
}

// ---------------- pre: bucket_count || xcast || prep ----------------
__global__ void pre_kernel(const void* eidx, const float* __restrict__ x,
                           const float* __restrict__ W1l, const float* __restrict__ W1r,
                           const float* __restrict__ W2l, const float* __restrict__ W2r,
                           const float* __restrict__ b2, const float* __restrict__ Wlp,
                           const float* __restrict__ blp,
                           int* __restrict__ blk_hist, unsigned short* __restrict__ xaown,
                           unsigned short* __restrict__ w1bf, float* __restrict__ wv,
                           int* __restrict__ flag,
                           long N, long E, int NBK, int chunk, int xcb) {
    int b = blockIdx.x;
    int tid = threadIdx.x;
    if (b < NBLK_A) {
        __shared__ int h[512];
        for (int i = tid; i < NBK; i += 256) h[i] = 0;
        __syncthreads();
        int is64 = detect64_local(eidx);
        long e0 = (long)b * chunk;
        long e1 = e0 + chunk; if (e1 > E) e1 = E;
        for (long e = e0 + tid; e < e1; e += 256) {
            long dst = load_idx(eidx, E + e, is64);
            atomicAdd(&h[(int)(dst >> 8)], 1);
        }
        __syncthreads();
        for (int i = tid; i < NBK; i += 256) blk_hist[i * NBLK_A + b] = h[i];
    } else if (b < NBLK_A + xcb) {
        long t = (long)(b - NBLK_A) * 256 + tid;
        long n = t >> 4;
        int q = (int)(t & 15);
        if (n >= N) return;
        float4 v = *(const float4*)&x[n * 64 + q * 4];
        uint2 u;
        u.x = (unsigned)f2bf(v.x) | ((unsigned)f2bf(v.y) << 16);
        u.y = (unsigned)f2bf(v.z) | ((unsigned)f2bf(v.w) << 16);
        *(uint2*)&xaown[n * 64 + q * 4] = u;
    } else {
        if (tid == 0) *flag = detect64_local(eidx);
        if (tid < 128) {
            int k = tid;
            float s0 = 0.f, s1 = 0.f, s2 = 0.f, s3 = 0.f;
            for (int o = 0; o < 64; ++o) {
                float wl = Wlp[o], wr = Wlp[64 + o];
                float l = W2l[o * 128 + k], r = W2r[o * 128 + k];
                s0 += wl * l; s1 += wr * l; s2 += wl * r; s3 += wr * r;
            }
            wv[k] = s0; wv[128 + k] = s1; wv[256 + k] = s2; wv[384 + k] = s3;
            if (k == 0) {
                float c = blp[0];
                for (int o = 0; o < 64; ++o) c += (Wlp[o] + Wlp[64 + o]) * b2[o];
                wv[512] = c;
            }
        }
        // W1' bf16, PRE-SWIZZLED: element (o*128+k) stored at index ^ ((o&7)<<3)
        for (int i = tid; i < 16384; i += 256) {
            int o = i >> 7, k = i & 127;
            float f = (k < 64) ? W1l[o * 64 + k] : W1r[o * 64 + (k - 64)];
            w1bf[i ^ ((o & 7) << 3)] = f2bf(f);
        }
    }
}

// relscan: blk_hist row -> exclusive within-row scan (no base); total[k] = row sum.
__global__ void bucket_relscan_kernel(int* __restrict__ blk_hist, int* __restrict__ total) {
    __shared__ int ts[256];
    int k = blockIdx.x, t = threadIdx.x;
    int v = blk_hist[k * NBLK_A + t];
    ts[t] = v; __syncthreads();
    for (int off = 1; off < 256; off <<= 1) {
        int u = (t >= off) ? ts[t - off] : 0;
        __syncthreads();
        ts[t] += u;
        __syncthreads();
    }
    blk_hist[k * NBLK_A + t] = ts[t] - v;
    if (t == 255) total[k] = ts[255];
}

// base: parallel exclusive scan over up to 512 bucket totals.
__global__ void base_kernel(const int* __restrict__ total, int* __restrict__ base,
                            int* __restrict__ row_start, int NBK, long N, long E) {
    __shared__ int ts[256];
    int t = threadIdx.x;
    int a = (t < NBK) ? total[t] : 0;
    int b = (256 + t < NBK) ? total[256 + t] : 0;
    ts[t] = a; __syncthreads();
    for (int off = 1; off < 256; off <<= 1) {
        int u = (t >= off) ? ts[t - off] : 0;
        __syncthreads();
        ts[t] += u;
        __syncthreads();
    }
    int incl1 = ts[t];
    int sum1 = ts[255];
    if (t < NBK) base[t] = incl1 - a;
    __syncthreads();
    ts[t] = b; __syncthreads();
    for (int off = 1; off < 256; off <<= 1) {
        int u = (t >= off) ? ts[t - off] : 0;
        __syncthreads();
        ts[t] += u;
        __syncthreads();
    }
    int incl2 = ts[t];
    if (256 + t < NBK) base[256 + t] = sum1 + incl2 - b;
    if (t == 255) base[NBK] = sum1 + incl2;
    if (t == 0) row_start[N] = (int)E;
}

// scatter: cursor = relative offset + base[k].
__global__ void bucket_scatter_kernel(const void* eidx, const int* flag,
                                      const int* __restrict__ blk_hist, const int* __restrict__ base,
                                      unsigned* __restrict__ ebuf, long E, int NBK, int chunk) {
    __shared__ int cur[512];
    int tid = threadIdx.x, b = blockIdx.x;
    for (int i = tid; i < NBK; i += 256) cur[i] = blk_hist[i * NBLK_A + b] + base[i];
    __syncthreads();
    int is64 = *flag;
    long e0 = (long)b * chunk;
    long e1 = e0 + chunk; if (e1 > E) e1 = E;
    for (long e = e0 + tid; e < e1; e += 256) {
        long src = load_idx(eidx, e, is64);
        long dst = load_idx(eidx, E + e, is64);
        int pos = atomicAdd(&cur[(int)(dst >> 8)], 1);
        ebuf[pos] = (unsigned)src | ((unsigned)(dst & 255) << 24);  // src < 2^24
    }
}

// per-bucket counting sort in LDS -> coalesced row_start + L2-local csr writes.
__global__ void bucket_csr_kernel(const unsigned* __restrict__ ebuf, const int* __restrict__ base,
                                  int* __restrict__ csr_src, int* __restrict__ row_start, long N) {
    __shared__ int cnt[256], sc[256], cur[256];
    int k = blockIdx.x, t = threadIdx.x;
    int bstart = base[k], bend = base[k + 1];
    cnt[t] = 0;
    __syncthreads();
    for (int i = bstart + t; i < bend; i += 256)
        atomicAdd(&cnt[ebuf[i] >> 24], 1);
    __syncthreads();
    int c = cnt[t];
    sc[t] = c; __syncthreads();
    for (int off = 1; off < 256; off <<= 1) {
        int u = (t >= off) ? sc[t - off] : 0;
        __syncthreads();
        sc[t] += u;
        __syncthreads();
    }
    int loff = sc[t] - c;
    cur[t] = loff;
    long n = (long)k * 256 + t;
    if (n < N) row_start[n] = bstart + loff;
    __syncthreads();
    for (int i = bstart + t; i < bend; i += 256) {
        unsigned v = ebuf[i];
        int dl = (int)(v >> 24);
        int p = atomicAdd(&cur[dl], 1);
        csr_src[bstart + p] = (int)(v & 0xFFFFFFu);
    }
}

// ---------------- gather: xagg[n][64] = mean_nbr xaown[src][64] ----------------
// One wave per node (100K waves). Lane l: edge slot lg=l>>4, feature quad fq=l&15.
// 16 edges/iter: 4 idx loads + 4 row loads -> 16 lines in flight. 32-bit addressing.
__global__ void gather_kernel(const int* __restrict__ rs, const int* __restrict__ csr,
                              const unsigned short* __restrict__ T,
                              unsigned short* __restrict__ Out, long N) {
    long gid = (long)blockIdx.x * 256 + threadIdx.x;
    long n = gid >> 6;
    if (n >= N) return;
    int lane = (int)(gid & 63);
    int lg = lane >> 4;
    int fq = lane & 15;
    int s = rs[n], e = rs[n + 1];
    unsigned boff = (unsigned)fq * 4u;
    float a0 = 0.f, a1 = 0.f, a2 = 0.f, a3 = 0.f;
    int j = s;
    for (; j + 16 <= e; j += 16) {
        unsigned o0 = ((unsigned)csr[j + lg] << 6) | boff;
        unsigned o1 = ((unsigned)csr[j + 4 + lg] << 6) | boff;
        unsigned o2 = ((unsigned)csr[j + 8 + lg] << 6) | boff;
        unsigned o3 = ((unsigned)csr[j + 12 + lg] << 6) | boff;
        uint2 r0 = *(const uint2*)&T[o0];
        uint2 r1 = *(const uint2*)&T[o1];
        uint2 r2 = *(const uint2*)&T[o2];
        uint2 r3 = *(const uint2*)&T[o3];
        a0 += uflo(r0.x); a1 += ufhi(r0.x); a2 += uflo(r0.y); a3 += ufhi(r0.y);
        a0 += uflo(r1.x); a1 += ufhi(r1.x); a2 += uflo(r1.y); a3 += ufhi(r1.y);
        a0 += uflo(r2.x); a1 += ufhi(r2.x); a2 += uflo(r2.y); a3 += ufhi(r2.y);
        a0 += uflo(r3.x); a1 += ufhi(r3.x); a2 += uflo(r3.y); a3 += ufhi(r3.y);
    }
    if (j < e) {
#pragma unroll
        for (int t = 0; t < 4; ++t) {
            int pos = j + 4 * t + lg;
            int ok = pos < e;
            unsigned oo = ((unsigned)csr[ok ? pos : s] << 6) | boff;
            uint2 r = *(const uint2*)&T[oo];
            float m = ok ? 1.f : 0.f;
            a0 += m * uflo(r.x); a1 += m * ufhi(r.x);
            a2 += m * uflo(r.y); a3 += m * ufhi(r.y);
        }
    }
    a0 += __shfl_xor(a0, 16, 64);  a1 += __shfl_xor(a1, 16, 64);
    a2 += __shfl_xor(a2, 16, 64);  a3 += __shfl_xor(a3, 16, 64);
    a0 += __shfl_xor(a0, 32, 64);  a1 += __shfl_xor(a1, 32, 64);
    a2 += __shfl_xor(a2, 32, 64);  a3 += __shfl_xor(a3, 32, 64);
    if (lg == 0) {
        float inv = 1.0f / fmaxf((float)(e - s), 1.0f);
        uint2 o;
        o.x = (unsigned)f2bf(a0 * inv) | ((unsigned)f2bf(a1 * inv) << 16);
        o.y = (unsigned)f2bf(a2 * inv) | ((unsigned)f2bf(a3 * inv) << 16);
        *(uint2*)&Out[((unsigned)n << 6) | boff] = o;
    }
}

// ---------------- fused MFMA GEMM + collapse: ab/cd = wv . relu(layer1([agg|own])) ----------------
// A'[n][k]: k<64 -> xagg[n][k]; k>=64 -> xaown[n][k-64]. Direct global bf16x8 loads.
// 512 thr = 8 waves x 16 nodes = 128 nodes/block. LDS = wbuf 32K + 2.5K -> 4 blocks/CU.
__global__ __launch_bounds__(512) void fused_gemm_kernel(
        const unsigned short* __restrict__ xagg, const unsigned short* __restrict__ xaown,
        const unsigned short* __restrict__ w1bf, const float* __restrict__ b1,
        const float* __restrict__ wv,
        float* __restrict__ ab, float* __restrict__ cd, long N) {
    __shared__ __align__(16) unsigned short wbuf[128 * 128];
    __shared__ float bs1[128];
    __shared__ float wvs[512];
    int tid = threadIdx.x;

    {   // stage pre-swizzled W1' (straight memcpy)
        const uint4* src = (const uint4*)w1bf;
        uint4* dst = (uint4*)wbuf;
#pragma unroll
        for (int i = 0; i < 4; ++i) dst[tid + i * 512] = src[tid + i * 512];
    }
    if (tid < 128) bs1[tid] = b1[tid];
    wvs[tid] = wv[tid];
    __syncthreads();

    int lane = tid & 63, wid = tid >> 6;
    int l16 = lane & 15, lg = lane >> 4;
    long n0 = (long)blockIdx.x * 128 + wid * 16;
    const unsigned short* Ag = xagg + (n0 + l16) * 64;
    const unsigned short* Ao = xaown + (n0 + l16) * 64;

    f32x4 acc[8];
#pragma unroll
    for (int ot = 0; ot < 8; ++ot) acc[ot] = (f32x4){0.f, 0.f, 0.f, 0.f};

    // ---- MFMA: h1 = relu(A' @ W1'.T + b1) ----
#pragma unroll
    for (int ks = 0; ks < 4; ++ks) {
        int k0 = ks * 32;
        bf16x8 a;
        if (ks < 2) a = *(const bf16x8*)&Ag[k0 + 8 * lg];
        else        a = *(const bf16x8*)&Ao[(k0 - 64) + 8 * lg];
#pragma unroll
        for (int ot = 0; ot < 8; ++ot) {
            int o = ot * 16 + l16;
            bf16x8 b = *(const bf16x8*)&wbuf[(o * 128 + k0 + 8 * lg) ^ ((o & 7) << 3)];
            acc[ot] = __builtin_amdgcn_mfma_f32_16x16x32_bf16(a, b, acc[ot], 0, 0, 0);
        }
    }

    // ---- phase 2 in registers: per row (node) da..dd = relu(h1+b1).wv[0..3] ----
#pragma unroll
    for (int j = 0; j < 4; ++j) {
        float da = 0.f, db = 0.f, dc = 0.f, dd = 0.f;
#pragma unroll
        for (int ot = 0; ot < 8; ++ot) {
            int col = ot * 16 + l16;
            float hv = fmaxf(acc[ot][j] + bs1[col], 0.f);
            da += hv * wvs[col];       db += hv * wvs[128 + col];
            dc += hv * wvs[256 + col]; dd += hv * wvs[384 + col];
        }
        da += __shfl_xor(da, 1, 64); db += __shfl_xor(db, 1, 64);
        dc += __shfl_xor(dc, 1, 64); dd += __shfl_xor(dd, 1, 64);
        da += __shfl_xor(da, 2, 64); db += __shfl_xor(db, 2, 64);
        dc += __shfl_xor(dc, 2, 64); dd += __shfl_xor(dd, 2, 64);
        da += __shfl_xor(da, 4, 64); db += __shfl_xor(db, 4, 64);
        dc += __shfl_xor(dc, 4, 64); dd += __shfl_xor(dd, 4, 64);
        da += __shfl_xor(da, 8, 64); db += __shfl_xor(db, 8, 64);
        dc += __shfl_xor(dc, 8, 64); dd += __shfl_xor(dd, 8, 64);
        long n = n0 + lg * 4 + j;
        if (l16 == 0 && n < N) {
            *(float2*)&ab[n * 2] = make_float2(da, db);
            *(float2*)&cd[n * 2] = make_float2(dc, dd);
        }
    }
}

// ---------------- scalar gather: UV[n] = (mean_nbr a + c[n], mean_nbr b + d[n]) ----------------
__global__ void sgather_kernel(const int* __restrict__ rs, const int* __restrict__ csr,
                               const float* __restrict__ ab, const float* __restrict__ cd,
                               float* __restrict__ UV, long N) {
    long n = (long)blockIdx.x * 256 + threadIdx.x;
    if (n >= N) return;
    int s = rs[n], e = rs[n + 1];
    float sa = 0.f, sb = 0.f;
    int j = s;
    for (; j + 4 <= e; j += 4) {
        unsigned i0 = (unsigned)csr[j] * 2u, i1 = (unsigned)csr[j + 1] * 2u;
        unsigned i2 = (unsigned)csr[j + 2] * 2u, i3 = (unsigned)csr[j + 3] * 2u;
        float2 v0 = *(const float2*)&ab[i0];
        float2 v1 = *(const float2*)&ab[i1];
        float2 v2 = *(const float2*)&ab[i2];
        float2 v3 = *(const float2*)&ab[i3];
        sa += (v0.x + v1.x) + (v2.x + v3.x);
        sb += (v0.y + v1.y) + (v2.y + v3.y);
    }
    for (; j < e; ++j) {
        float2 v = *(const float2*)&ab[(unsigned)csr[j] * 2u];
        sa += v.x; sb += v.y;
    }
    float inv = 1.0f / fmaxf((float)(e - s), 1.0f);
    float2 cdv = *(const float2*)&cd[n * 2];
    *(float2*)&UV[n * 2] = make_float2(sa * inv + cdv.x, sb * inv + cdv.y);
}

// linkpred: out[p] = sigmoid(U[s] + V[d] + C)
__global__ void linkpred_kernel(const void* pairs, const int* flag,
                                const float* __restrict__ UV, const float* __restrict__ wv,
                                float* __restrict__ out, long P) {
    long p = (long)blockIdx.x * 256 + threadIdx.x;
    if (p >= P) return;
    int is64 = *flag;
    long s = load_idx(pairs, 2 * p, is64);
    long d = load_idx(pairs, 2 * p + 1, is64);
    float acc = UV[s * 2] + UV[d * 2 + 1] + wv[512];
    out[p] = 1.0f / (1.0f + expf(-acc));
}

extern "C" void kernel_launch(void* const* d_in, const int* in_sizes, int n_in,
                              void* d_out, int out_size, void* d_ws, size_t ws_size,
                              hipStream_t stream) {
    const float* x    = (const float*)d_in[0];
    const void*  eidx  = d_in[1];
    const void*  pairs = d_in[2];
    const float* W1l = (const float*)d_in[3];
    const float* W1r = (const float*)d_in[4];
    const float* b1  = (const float*)d_in[5];
    const float* W2l = (const float*)d_in[6];
    const float* W2r = (const float*)d_in[7];
    const float* b2  = (const float*)d_in[8];
    const float* Wlp = (const float*)d_in[9];
    const float* blp = (const float*)d_in[10];
    float* out = (float*)d_out;

    long N = in_sizes[0] / 64;
    long E = in_sizes[1] / 2;
    long P = in_sizes[2] / 2;
    long NP = (N + 127) & ~127L;
    int NBK = (int)((N + 255) >> 8);          // <= 512
    int chunk = (int)((E + NBLK_A - 1) / NBLK_A);
    int xcb = (int)((N * 16 + 255) / 256);

    char* w = (char*)d_ws;
    auto alloc = [&](size_t bytes) {
        char* p = w;
        w += (bytes + 255) & ~(size_t)255;
        return p;
    };
    int* row_start = (int*)alloc((N + 1) * sizeof(int));
    int* csr_src   = (int*)alloc(E * sizeof(int));
    int* blk_hist  = (int*)alloc((size_t)NBK * NBLK_A * sizeof(int));
    int* total     = (int*)alloc(NBK * sizeof(int));
    int* base      = (int*)alloc((NBK + 1) * sizeof(int));
    int* flag      = (int*)alloc(64);
    unsigned* ebuf = (unsigned*)alloc(E * sizeof(unsigned));
    unsigned short* xaown = (unsigned short*)alloc((size_t)NP * 64 * 2);
    unsigned short* xagg  = (unsigned short*)alloc((size_t)NP * 64 * 2);
    unsigned short* w1bf  = (unsigned short*)alloc(16384 * 2);
    float* ab = (float*)alloc((size_t)N * 2 * sizeof(float));
    float* cd = (float*)alloc((size_t)N * 2 * sizeof(float));
    float* UV = (float*)alloc((size_t)N * 2 * sizeof(float));
    float* wv = (float*)alloc(1024 * sizeof(float));

    unsigned pre_blocks = (unsigned)(NBLK_A + xcb + 1);
    pre_kernel<<<pre_blocks, 256, 0, stream>>>(eidx, x, W1l, W1r, W2l, W2r, b2, Wlp, blp,
                                               blk_hist, xaown, w1bf, wv, flag,
                                               N, E, NBK, chunk, xcb);

    bucket_relscan_kernel<<<NBK, 256, 0, stream>>>(blk_hist, total);
    base_kernel<<<1, 256, 0, stream>>>(total, base, row_start, NBK, N, E);
    bucket_scatter_kernel<<<NBLK_A, 256, 0, stream>>>(eidx, flag, blk_hist, base, ebuf, E, NBK, chunk);
    bucket_csr_kernel<<<NBK, 256, 0, stream>>>(ebuf, base, csr_src, row_start, N);

    unsigned gth_blocks = (unsigned)((N * 64 + 255) / 256);
    gather_kernel<<<gth_blocks, 256, 0, stream>>>(row_start, csr_src, xaown, xagg, N);

    unsigned gblocks = (unsigned)(NP / 128);
    fused_gemm_kernel<<<gblocks, 512, 0, stream>>>(xagg, xaown, w1bf, b1, wv, ab, cd, N);

    unsigned sgblocks = (unsigned)((N + 255) / 256);
    sgather_kernel<<<sgblocks, 256, 0, stream>>>(row_start, csr_src, ab, cd, UV, N);

    unsigned pblocks = (unsigned)((P + 255) / 256);
    linkpred_kernel<<<pblocks, 256, 0, stream>>>(pairs, flag, UV, wv, out, P);
}